// Round 3
// baseline (260.813 us; speedup 1.0000x reference)
//
#include <hip/hip_runtime.h>
#include <hip/hip_cooperative_groups.h>

namespace cg = cooperative_groups;

typedef unsigned short u16;
typedef unsigned int u32;
typedef __attribute__((ext_vector_type(8))) short bf16x8;
typedef __attribute__((ext_vector_type(4))) float f32x4;

#define NUM_OPS 8
#define M_DIM 4096   // B*T
#define K_DIM 1024
#define N_DIM 1024
#define KITERS 16    // K / 64
#define UNROLL _Pragma("unroll")

// Fragment-tiled operands: 1KB chunks = 16 rows x 32 k; slot l (16B) holds
// rows (l&15), k=(l>>4)*8+j  == exact MFMA A/B fragment lane order.
// chunk index = rowtile*32 + ktile (ktile of 32 k).

// ---- helpers ----------------------------------------------------------

__device__ __forceinline__ u16 f2b(float f) {
  union { float f; u32 u; } v; v.f = f;
  u32 r = v.u + 0x7fffu + ((v.u >> 16) & 1u);  // RNE
  return (u16)(r >> 16);
}

__device__ __forceinline__ u32 pk2(float a, float b) {  // bf16(a) | bf16(b)<<16
  return (u32)f2b(a) | ((u32)f2b(b) << 16);
}

__device__ __forceinline__ int compute_idx(const float* __restrict__ logits,
                                           const float* __restrict__ u) {
  int best = 0; float bv = -3.4e38f;
UNROLL
  for (int i = 0; i < NUM_OPS; ++i) {
    float v = logits[i] - logf(-logf(u[i]));  // logits + gumbel
    if (v > bv) { bv = v; best = i; }
  }
  return best;
}

// async global->LDS, 16B/lane
__device__ __forceinline__ void gld_lds16(const void* g, void* l) {
  __builtin_amdgcn_global_load_lds(
      (__attribute__((address_space(1))) void*)(g),
      (__attribute__((address_space(3))) void*)(unsigned)(unsigned long long)(l),
      16, 0, 0);
}

// ---- phase 0a: convert this block's x slice into frag-tiled xb ---------
__device__ __forceinline__ void do_xchunks(const float* __restrict__ x,
                                           u16* __restrict__ xb,
                                           int mb, int nb, int w, int l) {
UNROLL
  for (int it = 0; it < 4; ++it) {
    const int chunk = mb * 128 + nb * 16 + it * 4 + w;  // [0,8192) bijective
    const int mtile = chunk >> 5, ktile = chunk & 31;
    const float* src = x + (size_t)(mtile * 16 + (l & 15)) * K_DIM
                         + ktile * 32 + (l >> 4) * 8;
    float4 f0 = *(const float4*)(src);
    float4 f1 = *(const float4*)(src + 4);
    uint4 p;
    p.x = pk2(f0.x, f0.y); p.y = pk2(f0.z, f0.w);
    p.z = pk2(f1.x, f1.y); p.w = pk2(f1.z, f1.w);
    *(uint4*)(xb + (size_t)chunk * 512 + l * 8) = p;
  }
}

// ---- phase 0b: transpose one 64x64 W-tile into frag-tiled wt -----------
__device__ __forceinline__ void do_wtile(const float* __restrict__ W,
                                         const float* __restrict__ logits,
                                         const float* __restrict__ u,
                                         u16* __restrict__ wt,
                                         u16 (*t)[66], int wb, int tid) {
  const int kt = wb >> 4, nt = wb & 15;   // 64x64 tile of W[k][n]
  const int idx = compute_idx(logits, u);
  const float* Wi = W + (size_t)idx * K_DIM * N_DIM;
UNROLL
  for (int it = 0; it < 16; ++it) {
    int i = it * 256 + tid;
    int r = i >> 6, c = i & 63;
    t[r][c] = f2b(Wi[(size_t)(kt * 64 + r) * N_DIM + nt * 64 + c]);
  }
  __syncthreads();
UNROLL
  for (int it = 0; it < 2; ++it) {
    int s = it * 256 + tid;
    int c = s >> 6, l = s & 63;
    int ntl = c & 3, ktl = c >> 2;
    int kb = ktl * 32 + (l >> 4) * 8, nn = ntl * 16 + (l & 15);
    uint4 p;
    p.x = (u32)t[kb + 0][nn] | ((u32)t[kb + 1][nn] << 16);
    p.y = (u32)t[kb + 2][nn] | ((u32)t[kb + 3][nn] << 16);
    p.z = (u32)t[kb + 4][nn] | ((u32)t[kb + 5][nn] << 16);
    p.w = (u32)t[kb + 6][nn] | ((u32)t[kb + 7][nn] << 16);
    int chunk = (nt * 4 + ntl) * 32 + (kt * 2 + ktl);
    *(uint4*)(wt + (size_t)chunk * 512 + l * 8) = p;
  }
}

// ---- GEMM body (R0-verified structure), shared by fused + fallback -----
// BM=64, BN=128, BK=64; 256 thr = 4 waves (2m x 2n), wave tile 32x64.
// 24 chunks/iter staged via gld_lds16 (6/wave), dbuf, one barrier/iter.
__device__ __forceinline__ void gemm_body(
    const u16* __restrict__ xb, const u16* __restrict__ wt,
    const float* __restrict__ bvec, const float* __restrict__ logits,
    const float* __restrict__ u, float* __restrict__ out,
    u16 (*sm)[24 * 512], int tid, int bid) {
  const int w = tid >> 6, L = tid & 63;
  const int mb = (bid & 7) * 8 + (bid >> 6);   // [0,64): XCD-local m-slabs
  const int nb = (bid >> 3) & 7;               // [0,8)

  // staging: wave w handles items 6w..6w+5; item<8 -> A chunk, else B
  const u16* gsrc[6];
  int lofs[6];
UNROLL
  for (int j = 0; j < 6; ++j) {
    int item = 6 * w + j;
    if (item < 8) {
      int mt = item >> 1, dk = item & 1;
      gsrc[j] = xb + ((size_t)((mb * 4 + mt) * 32 + dk)) * 512 + L * 8;
    } else {
      int t = item - 8, nt = t >> 1, dk = t & 1;
      gsrc[j] = wt + ((size_t)((nb * 8 + nt) * 32 + dk)) * 512 + L * 8;
    }
    lofs[j] = item * 512 + L * 8;
  }

  const int wm = w & 1, wn = w >> 1;
  int aoff[2][2], boff[4][2];
UNROLL
  for (int f = 0; f < 2; ++f)
UNROLL
    for (int dk = 0; dk < 2; ++dk)
      aoff[f][dk] = ((2 * wm + f) * 2 + dk) * 512 + L * 8;
UNROLL
  for (int t = 0; t < 4; ++t)
UNROLL
    for (int dk = 0; dk < 2; ++dk)
      boff[t][dk] = (8 + (4 * wn + t) * 2 + dk) * 512 + L * 8;

  f32x4 acc[2][4] = {};

  // prologue: stage k-iter 0 into buf 0
UNROLL
  for (int j = 0; j < 6; ++j) gld_lds16(gsrc[j], &sm[0][lofs[j]]);

  for (int kk = 0; kk < KITERS; ++kk) {
    const int cur = kk & 1, nxt = cur ^ 1;
    __syncthreads();  // drains own staging (vmcnt); all waves' chunks landed

    if (kk + 1 < KITERS) {
      const int ko = (kk + 1) * 1024;  // 2 ktiles per iter, 512 u16 each
UNROLL
      for (int j = 0; j < 6; ++j) gld_lds16(gsrc[j] + ko, &sm[nxt][lofs[j]]);
    }

    bf16x8 af[2][2], bf[4][2];
UNROLL
    for (int f = 0; f < 2; ++f)
UNROLL
      for (int dk = 0; dk < 2; ++dk)
        af[f][dk] = *(const bf16x8*)(&sm[cur][aoff[f][dk]]);
UNROLL
    for (int t = 0; t < 4; ++t)
UNROLL
      for (int dk = 0; dk < 2; ++dk)
        bf[t][dk] = *(const bf16x8*)(&sm[cur][boff[t][dk]]);
UNROLL
    for (int dk = 0; dk < 2; ++dk)
UNROLL
      for (int f = 0; f < 2; ++f)
UNROLL
        for (int t = 0; t < 4; ++t)
          acc[f][t] = __builtin_amdgcn_mfma_f32_16x16x32_bf16(
              af[f][dk], bf[t][dk], acc[f][t], 0, 0, 0);
    // no trailing barrier: buf[nxt] writers are gated by this iter's barrier
  }

  // epilogue: C/D layout col=lane&15, row=(lane>>4)*4+reg
  const int idx = compute_idx(logits, u);
  const float* bi = bvec + (size_t)idx * N_DIM;
UNROLL
  for (int f = 0; f < 2; ++f) {
    int row = mb * 64 + 32 * wm + 16 * f + (L >> 4) * 4;
UNROLL
    for (int t = 0; t < 4; ++t) {
      int col = nb * 128 + 64 * wn + 16 * t + (L & 15);
      float bv = bi[col];
UNROLL
      for (int r = 0; r < 4; ++r)
        out[(size_t)(row + r) * N_DIM + col] = acc[f][t][r] + bv;
    }
  }
}

// ---- fused cooperative kernel: prep phase + grid sync + GEMM -----------
__global__ __launch_bounds__(256, 2) void fused_kernel(
    const float* __restrict__ x, const float* __restrict__ W,
    const float* __restrict__ bvec, const float* __restrict__ logits,
    const float* __restrict__ u, u16* __restrict__ xb, u16* __restrict__ wt,
    float* __restrict__ out) {
  __shared__ u16 sm[2][24 * 512];  // 48 KB: GEMM dbuf; overlaid by W-transpose

  const int tid = threadIdx.x;
  const int bid = blockIdx.x;
  const int w = tid >> 6, L = tid & 63;
  const int mb = (bid & 7) * 8 + (bid >> 6);
  const int nb = (bid >> 3) & 7;

  // phase 0: each block converts the 16 x-chunks its own tile reads
  // (XCD-local under the bid swizzle); blocks 0..255 also transpose one
  // W-tile using sm[0] as scratch (4224 u16 < 12288).
  do_xchunks(x, xb, mb, nb, w, L);
  if (bid < 256)
    do_wtile(W, logits, u, wt, (u16(*)[66]) & sm[0][0], bid, tid);

  // cross-XCD visibility: release (L2 writeback) -> barrier -> acquire (inv)
  __threadfence();
  cg::this_grid().sync();
  __threadfence();

  gemm_body(xb, wt, bvec, logits, u, out, sm, tid, bid);
}

// ---- fallback two-kernel path (verified R0) ----------------------------
__global__ void prep_kernel(const float* __restrict__ x, const float* __restrict__ W,
                            const float* __restrict__ logits, const float* __restrict__ u,
                            u16* __restrict__ xb, u16* __restrict__ wt) {
  const int tid = threadIdx.x;
  const int bid = blockIdx.x;
  if (bid < 2048) {
    const int chunk = bid * 4 + (tid >> 6), l = tid & 63;
    const int mtile = chunk >> 5, ktile = chunk & 31;
    const float* src = x + (size_t)(mtile * 16 + (l & 15)) * K_DIM
                         + ktile * 32 + (l >> 4) * 8;
    float4 f0 = *(const float4*)(src);
    float4 f1 = *(const float4*)(src + 4);
    uint4 p;
    p.x = pk2(f0.x, f0.y); p.y = pk2(f0.z, f0.w);
    p.z = pk2(f1.x, f1.y); p.w = pk2(f1.z, f1.w);
    *(uint4*)(xb + (size_t)chunk * 512 + l * 8) = p;
  } else {
    __shared__ u16 t[64][66];
    do_wtile(W, logits, u, wt, t, bid - 2048, tid);
  }
}

__global__ __launch_bounds__(256) void gemm_kernel(
    const u16* __restrict__ xb, const u16* __restrict__ wt,
    const float* __restrict__ bvec, const float* __restrict__ logits,
    const float* __restrict__ u, float* __restrict__ out) {
  __shared__ u16 sm[2][24 * 512];
  gemm_body(xb, wt, bvec, logits, u, out, sm, threadIdx.x, blockIdx.x);
}

// ---- launch -----------------------------------------------------------

extern "C" void kernel_launch(void* const* d_in, const int* in_sizes, int n_in,
                              void* d_out, int out_size, void* d_ws, size_t ws_size,
                              hipStream_t stream) {
  const float* x      = (const float*)d_in[0];
  const float* W      = (const float*)d_in[1];
  const float* bvec   = (const float*)d_in[2];
  const float* logits = (const float*)d_in[3];
  const float* u      = (const float*)d_in[4];
  float* out = (float*)d_out;

  u16* xb = (u16*)d_ws;                          // frag-tiled x, 8 MB
  u16* wt = (u16*)d_ws + (size_t)M_DIM * K_DIM;  // frag-tiled W[idx], 2 MB

  void* args[] = {(void*)&x, (void*)&W, (void*)&bvec, (void*)&logits,
                  (void*)&u, (void*)&xb, (void*)&wt, (void*)&out};
  hipError_t e = hipLaunchCooperativeKernel((const void*)fused_kernel,
                                            dim3(512), dim3(256), args, 0, stream);
  if (e != hipSuccess) {
    // graph-capture or co-residency rejection: run the verified 2-kernel path
    prep_kernel<<<2048 + 256, 256, 0, stream>>>(x, W, logits, u, xb, wt);
    gemm_kernel<<<512, 256, 0, stream>>>(xb, wt, bvec, logits, u, out);
  }
}

// Round 4
// 107.886 us; speedup vs baseline: 2.4175x; 2.4175x over previous
//
#include <hip/hip_runtime.h>

typedef unsigned short u16;
typedef unsigned int u32;
typedef __attribute__((ext_vector_type(8))) short bf16x8;
typedef __attribute__((ext_vector_type(4))) float f32x4;

#define NUM_OPS 8
#define M_DIM 4096   // B*T
#define K_DIM 1024
#define N_DIM 1024
#define KITERS 16    // K / 64
#define UNROLL _Pragma("unroll")

// Fragment-tiled operands: 1KB chunks = 16 rows x 32 k; slot l (16B) holds
// rows (l&15), k=(l>>4)*8+j  == exact MFMA A/B fragment lane order.
// chunk index = rowtile*32 + ktile (ktile of 32 k).

// ---- helpers ----------------------------------------------------------

__device__ __forceinline__ u16 f2b(float f) {
  union { float f; u32 u; } v; v.f = f;
  u32 r = v.u + 0x7fffu + ((v.u >> 16) & 1u);  // RNE
  return (u16)(r >> 16);
}

__device__ __forceinline__ u32 pk2(float a, float b) {  // bf16(a) | bf16(b)<<16
  return (u32)f2b(a) | ((u32)f2b(b) << 16);
}

__device__ __forceinline__ int compute_idx(const float* __restrict__ logits,
                                           const float* __restrict__ u) {
  int best = 0; float bv = -3.4e38f;
UNROLL
  for (int i = 0; i < NUM_OPS; ++i) {
    float v = logits[i] - logf(-logf(u[i]));  // logits + gumbel
    if (v > bv) { bv = v; best = i; }
  }
  return best;
}

// async global->LDS, 16B/lane
__device__ __forceinline__ void gld_lds16(const void* g, void* l) {
  __builtin_amdgcn_global_load_lds(
      (__attribute__((address_space(1))) void*)(g),
      (__attribute__((address_space(3))) void*)(unsigned)(unsigned long long)(l),
      16, 0, 0);
}

// ---- prep: x -> xb (frag-tiled bf16), W[idx] -> wt (frag-tiled bf16) ----
// (identical to the verified round-0 version)
__global__ void prep_kernel(const float* __restrict__ x, const float* __restrict__ W,
                            const float* __restrict__ logits, const float* __restrict__ u,
                            u16* __restrict__ xb, u16* __restrict__ wt) {
  const int tid = threadIdx.x;
  const int bid = blockIdx.x;
  if (bid < 2048) {
    const int chunk = bid * 4 + (tid >> 6), l = tid & 63;
    const int mtile = chunk >> 5, ktile = chunk & 31;
    const float* src = x + (size_t)(mtile * 16 + (l & 15)) * K_DIM
                         + ktile * 32 + (l >> 4) * 8;
    float4 f0 = *(const float4*)(src);
    float4 f1 = *(const float4*)(src + 4);
    uint4 p;
    p.x = pk2(f0.x, f0.y); p.y = pk2(f0.z, f0.w);
    p.z = pk2(f1.x, f1.y); p.w = pk2(f1.z, f1.w);
    *(uint4*)(xb + (size_t)chunk * 512 + l * 8) = p;
  } else {
    __shared__ u16 t[64][66];  // [k][n], +2 pad
    const int wb = bid - 2048;
    const int kt = wb >> 4, nt = wb & 15;   // 64x64 tile of W[k][n]
    const int idx = compute_idx(logits, u);
    const float* Wi = W + (size_t)idx * K_DIM * N_DIM;
UNROLL
    for (int it = 0; it < 16; ++it) {
      int i = it * 256 + tid;
      int r = i >> 6, c = i & 63;
      t[r][c] = f2b(Wi[(size_t)(kt * 64 + r) * N_DIM + nt * 64 + c]);
    }
    __syncthreads();
UNROLL
    for (int it = 0; it < 2; ++it) {
      int s = it * 256 + tid;
      int c = s >> 6, l = s & 63;
      int ntl = c & 3, ktl = c >> 2;
      int kb = ktl * 32 + (l >> 4) * 8, nn = ntl * 16 + (l & 15);
      uint4 p;
      p.x = (u32)t[kb + 0][nn] | ((u32)t[kb + 1][nn] << 16);
      p.y = (u32)t[kb + 2][nn] | ((u32)t[kb + 3][nn] << 16);
      p.z = (u32)t[kb + 4][nn] | ((u32)t[kb + 5][nn] << 16);
      p.w = (u32)t[kb + 6][nn] | ((u32)t[kb + 7][nn] << 16);
      int chunk = (nt * 4 + ntl) * 32 + (kt * 2 + ktl);
      *(uint4*)(wt + (size_t)chunk * 512 + l * 8) = p;
    }
  }
}

// ---- GEMM: out = x * W[idx] + b[idx] -----------------------------------
// BM=64, BN=128, BK=64; 256 thr = 4 waves (2m x 2n), wave tile 32x64.
// MIXED OPERAND DELIVERY:
//   B: R0-verified LDS double-buffer via gld_lds16 (16 chunks/iter, 4/wave),
//      one barrier per k-iter, no trailing barrier.
//   A: direct frag-tiled loads xb -> VGPR (R2-verified addressing), 2-deep
//      named register pipeline (aA/aB -> static indexing, no scratch).
//      A-loads for k+2 issue AFTER the MFMAs consuming that set (WAR-safe);
//      the barrier vmcnt drain on them is hidden by the 2nd block per CU.
// LDS traffic/CU-iter: 144KB -> 96KB (-33%). A's 8KB/iter working set is
// L1-resident so the duplicate read by the two wn-waves is cheap.
__global__ __launch_bounds__(256) void gemm_kernel(
    const u16* __restrict__ xb, const u16* __restrict__ wt,
    const float* __restrict__ bvec, const float* __restrict__ logits,
    const float* __restrict__ u, float* __restrict__ out) {
  __shared__ u16 sm[2][16 * 512];  // B chunks only, 16KB per buf

  const int tid = threadIdx.x;
  const int w = tid >> 6, L = tid & 63;
  const int bid = blockIdx.x;
  const int mb = (bid & 7) * 8 + (bid >> 6);   // [0,64): XCD-local m-slabs
  const int nb = (bid >> 3) & 7;               // [0,8)
  const int wm = w & 1, wn = w >> 1;

  // B staging: wave w handles items 4w..4w+3
  const u16* bsrc[4];
  int blofs[4];
UNROLL
  for (int j = 0; j < 4; ++j) {
    int item = 4 * w + j;
    int nt = item >> 1, dk = item & 1;
    bsrc[j] = wt + ((size_t)((nb * 8 + nt) * 32 + dk)) * 512 + L * 8;
    blofs[j] = item * 512 + L * 8;
  }

  // B read offsets
  int boff[4][2];
UNROLL
  for (int t = 0; t < 4; ++t)
UNROLL
    for (int dk = 0; dk < 2; ++dk)
      boff[t][dk] = ((4 * wn + t) * 2 + dk) * 512 + L * 8;

  // A: direct fragment base; frag (f,dk) at k-iter k lives at
  //   abase + (f*32 + k*2 + dk)*512    (elements; chunk = 512 u16 = 1KB)
  const u16* abase = xb + (size_t)((mb * 4 + 2 * wm) * 32) * 512 + L * 8;

  f32x4 acc[2][4] = {};
  bf16x8 aA[2][2], aB[2][2];

#define LOADA(S, k) do {                                                  \
  UNROLL                                                                  \
  for (int f_ = 0; f_ < 2; ++f_)                                          \
    UNROLL                                                                \
    for (int d_ = 0; d_ < 2; ++d_)                                        \
      S[f_][d_] = *(const bf16x8*)(abase + (f_ * 32 + (k) * 2 + d_) * 512); \
} while (0)

#define STAGE_B(k, bufi) do {                                             \
  const int ko_ = (k) * 1024;  /* 2 ktiles per iter, 512 u16 each */      \
  UNROLL                                                                  \
  for (int j_ = 0; j_ < 4; ++j_)                                          \
    gld_lds16(bsrc[j_] + ko_, &sm[bufi][blofs[j_]]);                      \
} while (0)

#define BODY(S, k, bufi) do {                                             \
  __syncthreads();  /* drains vmcnt: B[bufi] landed, S's A-frags ready */ \
  if ((k) + 1 < KITERS) STAGE_B((k) + 1, (bufi) ^ 1);                     \
  bf16x8 bf_[4][2];                                                       \
  UNROLL                                                                  \
  for (int t_ = 0; t_ < 4; ++t_)                                          \
    UNROLL                                                                \
    for (int d_ = 0; d_ < 2; ++d_)                                        \
      bf_[t_][d_] = *(const bf16x8*)(&sm[bufi][boff[t_][d_]]);            \
  UNROLL                                                                  \
  for (int d_ = 0; d_ < 2; ++d_)                                          \
    UNROLL                                                                \
    for (int f_ = 0; f_ < 2; ++f_)                                        \
      UNROLL                                                              \
      for (int t_ = 0; t_ < 4; ++t_)                                      \
        acc[f_][t_] = __builtin_amdgcn_mfma_f32_16x16x32_bf16(            \
            S[f_][d_], bf_[t_][d_], acc[f_][t_], 0, 0, 0);                \
  if ((k) + 2 < KITERS) LOADA(S, (k) + 2);  /* after consumption: WAR-safe */ \
} while (0)

  // prologue: A0, B0, A1 in flight; first barrier drains all
  LOADA(aA, 0);
  STAGE_B(0, 0);
  LOADA(aB, 1);

  for (int kk = 0; kk < KITERS; kk += 2) {
    BODY(aA, kk, 0);
    BODY(aB, kk + 1, 1);
  }

  // epilogue: C/D layout col=lane&15, row=(lane>>4)*4+reg
  const int idx = compute_idx(logits, u);
  const float* bi = bvec + (size_t)idx * N_DIM;
UNROLL
  for (int f = 0; f < 2; ++f) {
    int row = mb * 64 + 32 * wm + 16 * f + (L >> 4) * 4;
UNROLL
    for (int t = 0; t < 4; ++t) {
      int col = nb * 128 + 64 * wn + 16 * t + (L & 15);
      float bv = bi[col];
UNROLL
      for (int r = 0; r < 4; ++r)
        out[(size_t)(row + r) * N_DIM + col] = acc[f][t][r] + bv;
    }
  }
}

// ---- launch -----------------------------------------------------------

extern "C" void kernel_launch(void* const* d_in, const int* in_sizes, int n_in,
                              void* d_out, int out_size, void* d_ws, size_t ws_size,
                              hipStream_t stream) {
  const float* x      = (const float*)d_in[0];
  const float* W      = (const float*)d_in[1];
  const float* bvec   = (const float*)d_in[2];
  const float* logits = (const float*)d_in[3];
  const float* u      = (const float*)d_in[4];
  float* out = (float*)d_out;

  u16* xb = (u16*)d_ws;                          // frag-tiled x, 8 MB
  u16* wt = (u16*)d_ws + (size_t)M_DIM * K_DIM;  // frag-tiled W[idx], 2 MB

  prep_kernel<<<2048 + 256, 256, 0, stream>>>(x, W, logits, u, xb, wt);
  gemm_kernel<<<512, 256, 0, stream>>>(xb, wt, bvec, logits, u, out);
}

// Round 5
// 106.167 us; speedup vs baseline: 2.4566x; 1.0162x over previous
//
#include <hip/hip_runtime.h>

typedef unsigned short u16;
typedef unsigned int u32;
typedef __attribute__((ext_vector_type(8))) short bf16x8;
typedef __attribute__((ext_vector_type(4))) float f32x4;

#define NUM_OPS 8
#define M_DIM 4096   // B*T
#define K_DIM 1024
#define N_DIM 1024
#define BK 64
#define KITERS (K_DIM / BK)   // 16
// Fragment-tiled operands: 1KB chunks = 16 rows x 32 k; slot l (16B) holds
// rows (l&15), k=(l>>4)*8+j  == exact MFMA A/B fragment lane order.
// chunk index = rowtile*32 + ktile (ktile of 32).

// ---- helpers ----------------------------------------------------------

__device__ __forceinline__ u16 f2b(float f) {
  union { float f; u32 u; } v; v.f = f;
  u32 r = v.u + 0x7fffu + ((v.u >> 16) & 1u);  // RNE
  return (u16)(r >> 16);
}

__device__ __forceinline__ u32 pk2(float a, float b) {  // bf16(a) | bf16(b)<<16
  return (u32)f2b(a) | ((u32)f2b(b) << 16);
}

__device__ __forceinline__ int compute_idx(const float* __restrict__ logits,
                                           const float* __restrict__ u) {
  int best = 0; float bv = -3.4e38f;
#pragma unroll
  for (int i = 0; i < NUM_OPS; ++i) {
    float v = logits[i] - logf(-logf(u[i]));  // logits + gumbel
    if (v > bv) { bv = v; best = i; }
  }
  return best;
}

// async global->LDS, 16B/lane
__device__ __forceinline__ void gld_lds16(const void* g, void* l) {
  __builtin_amdgcn_global_load_lds(
      (__attribute__((address_space(1))) void*)(g),
      (__attribute__((address_space(3))) void*)(unsigned)(unsigned long long)(l),
      16, 0, 0);
}

// ---- prep: x -> xb (frag-tiled bf16), W[idx] -> wt (frag-tiled bf16) ----
__global__ void prep_kernel(const float* __restrict__ x, const float* __restrict__ W,
                            const float* __restrict__ logits, const float* __restrict__ u,
                            u16* __restrict__ xb, u16* __restrict__ wt) {
  const int tid = threadIdx.x;
  const int bid = blockIdx.x;
  if (bid < 2048) {
    const int chunk = bid * 4 + (tid >> 6), l = tid & 63;
    const int mtile = chunk >> 5, ktile = chunk & 31;
    const float* src = x + (size_t)(mtile * 16 + (l & 15)) * K_DIM
                         + ktile * 32 + (l >> 4) * 8;
    float4 f0 = *(const float4*)(src);
    float4 f1 = *(const float4*)(src + 4);
    uint4 p;
    p.x = pk2(f0.x, f0.y); p.y = pk2(f0.z, f0.w);
    p.z = pk2(f1.x, f1.y); p.w = pk2(f1.z, f1.w);
    *(uint4*)(xb + (size_t)chunk * 512 + l * 8) = p;
  } else {
    __shared__ u16 t[64][66];  // [k][n], +2 pad
    const int wb = bid - 2048;
    const int kt = wb >> 4, nt = wb & 15;   // 64x64 tile of W[k][n]
    const int idx = compute_idx(logits, u);
    const float* Wi = W + (size_t)idx * K_DIM * N_DIM;
#pragma unroll
    for (int it = 0; it < 16; ++it) {
      int i = it * 256 + tid;
      int r = i >> 6, c = i & 63;
      t[r][c] = f2b(Wi[(size_t)(kt * 64 + r) * N_DIM + nt * 64 + c]);
    }
    __syncthreads();
#pragma unroll
    for (int it = 0; it < 2; ++it) {
      int s = it * 256 + tid;
      int c = s >> 6, l = s & 63;
      int ntl = c & 3, ktl = c >> 2;
      int kb = ktl * 32 + (l >> 4) * 8, nn = ntl * 16 + (l & 15);
      uint4 p;
      p.x = (u32)t[kb + 0][nn] | ((u32)t[kb + 1][nn] << 16);
      p.y = (u32)t[kb + 2][nn] | ((u32)t[kb + 3][nn] << 16);
      p.z = (u32)t[kb + 4][nn] | ((u32)t[kb + 5][nn] << 16);
      p.w = (u32)t[kb + 6][nn] | ((u32)t[kb + 7][nn] << 16);
      int chunk = (nt * 4 + ntl) * 32 + (kt * 2 + ktl);
      *(uint4*)(wt + (size_t)chunk * 512 + l * 8) = p;
    }
  }
}

// ---- GEMM: out = x * W[idx] + b[idx] -----------------------------------
// BM=64, BN=128, BK=64; 256 thr = 4 waves (2m x 2n), wave tile 32x64.
// Grid 512 = 2 blocks/CU: two INDEPENDENT barrier groups per CU -> 2
// waves/SIMD interleave (one computes while the other drains/stages).
// 24 chunks/iter staged via gld_lds16 (6/wave), dbuf, one barrier/iter.
__global__ __launch_bounds__(256) void gemm_kernel(
    const u16* __restrict__ xb, const u16* __restrict__ wt,
    const float* __restrict__ bvec, const float* __restrict__ logits,
    const float* __restrict__ u, float* __restrict__ out) {
  // unified chunk store: A chunks 0..7, B chunks 8..23 (24 KB per buf)
  __shared__ u16 sm[2][24 * 512];

  const int tid = threadIdx.x;
  const int w = tid >> 6, L = tid & 63;
  const int bid = blockIdx.x;
  const int mb = (bid & 7) * 8 + (bid >> 6);   // [0,64): XCD-local m-slabs
  const int nb = (bid >> 3) & 7;               // [0,8)

  // staging: wave w handles items 6w..6w+5; item<8 -> A chunk, else B
  const u16* gsrc[6];
  int lofs[6];
#pragma unroll
  for (int j = 0; j < 6; ++j) {
    int item = 6 * w + j;
    if (item < 8) {
      int mt = item >> 1, dk = item & 1;
      gsrc[j] = xb + ((size_t)((mb * 4 + mt) * 32 + dk)) * 512 + L * 8;
    } else {
      int t = item - 8, nt = t >> 1, dk = t & 1;
      gsrc[j] = wt + ((size_t)((nb * 8 + nt) * 32 + dk)) * 512 + L * 8;
    }
    lofs[j] = item * 512 + L * 8;
  }

  const int wm = w & 1, wn = w >> 1;
  int aoff[2][2], boff[4][2];
#pragma unroll
  for (int f = 0; f < 2; ++f)
#pragma unroll
    for (int dk = 0; dk < 2; ++dk)
      aoff[f][dk] = ((2 * wm + f) * 2 + dk) * 512 + L * 8;
#pragma unroll
  for (int t = 0; t < 4; ++t)
#pragma unroll
    for (int dk = 0; dk < 2; ++dk)
      boff[t][dk] = (8 + (4 * wn + t) * 2 + dk) * 512 + L * 8;

  f32x4 acc[2][4] = {};

  // prologue: stage k-iter 0 into buf 0
#pragma unroll
  for (int j = 0; j < 6; ++j) gld_lds16(gsrc[j], &sm[0][lofs[j]]);

  for (int kk = 0; kk < KITERS; ++kk) {
    const int cur = kk & 1, nxt = cur ^ 1;
    __syncthreads();  // drains own staging (vmcnt); all waves' chunks landed

    if (kk + 1 < KITERS) {
      const int ko = (kk + 1) * 1024;  // 2 ktiles per iter, 512 u16 each
#pragma unroll
      for (int j = 0; j < 6; ++j) gld_lds16(gsrc[j] + ko, &sm[nxt][lofs[j]]);
    }

    bf16x8 af[2][2], bf[4][2];
#pragma unroll
    for (int f = 0; f < 2; ++f)
#pragma unroll
      for (int dk = 0; dk < 2; ++dk)
        af[f][dk] = *(const bf16x8*)(&sm[cur][aoff[f][dk]]);
#pragma unroll
    for (int t = 0; t < 4; ++t)
#pragma unroll
      for (int dk = 0; dk < 2; ++dk)
        bf[t][dk] = *(const bf16x8*)(&sm[cur][boff[t][dk]]);
#pragma unroll
    for (int dk = 0; dk < 2; ++dk)
#pragma unroll
      for (int f = 0; f < 2; ++f)
#pragma unroll
        for (int t = 0; t < 4; ++t)
          acc[f][t] = __builtin_amdgcn_mfma_f32_16x16x32_bf16(
              af[f][dk], bf[t][dk], acc[f][t], 0, 0, 0);
    // no trailing barrier: buf[nxt] writers are gated by this iter's barrier
  }

  // epilogue: C/D layout col=lane&15, row=(lane>>4)*4+reg
  const int idx = compute_idx(logits, u);
  const float* bi = bvec + (size_t)idx * N_DIM;
#pragma unroll
  for (int f = 0; f < 2; ++f) {
    int row = mb * 64 + 32 * wm + 16 * f + (L >> 4) * 4;
#pragma unroll
    for (int t = 0; t < 4; ++t) {
      int col = nb * 128 + 64 * wn + 16 * t + (L & 15);
      float bv = bi[col];
#pragma unroll
      for (int r = 0; r < 4; ++r)
        out[(size_t)(row + r) * N_DIM + col] = acc[f][t][r] + bv;
    }
  }
}

// ---- launch -----------------------------------------------------------

extern "C" void kernel_launch(void* const* d_in, const int* in_sizes, int n_in,
                              void* d_out, int out_size, void* d_ws, size_t ws_size,
                              hipStream_t stream) {
  const float* x      = (const float*)d_in[0];
  const float* W      = (const float*)d_in[1];
  const float* bvec   = (const float*)d_in[2];
  const float* logits = (const float*)d_in[3];
  const float* u      = (const float*)d_in[4];
  float* out = (float*)d_out;

  u16* xb = (u16*)d_ws;                          // frag-tiled x, 8 MB
  u16* wt = (u16*)d_ws + (size_t)M_DIM * K_DIM;  // frag-tiled W[idx], 2 MB

  prep_kernel<<<2048 + 256, 256, 0, stream>>>(x, W, logits, u, xb, wt);
  gemm_kernel<<<512, 256, 0, stream>>>(xb, wt, bvec, logits, u, out);
}